// Round 2
// baseline (170.464 us; speedup 1.0000x reference)
//
#include <hip/hip_runtime.h>
#include <stdint.h>

// VectorQuantizer on MI355X — round 9: barrier-free K-loop, spill-free regs.
// R8 post-mortem: (512,4) launch bounds -> 128-reg cap -> ~111 MB spill
// round-trip (WRITE 37->147 MB, FETCH 42->155 MB symmetric), MfmaUtil 6.7.
// The barrier-free global-B read itself was validated: net fetch minus spill
// equals R7's 42 MB, i.e. Ebf B-reads are fully L2-absorbed.
// R9: keep barrier-free K-loop; 256-thread/4-wave blocks, launch_bounds
// (256,3) -> 170 regs/wave (acc[4][4]=64 + operands ~120 live, no spill),
// 3 blocks/CU = 12 waves/CU. ms loop = 4 quarters of 256 codes. B-loads
// hand-prefetched 1 chunk ahead to overlap ~200cy L2 latency with 16 MFMAs.
// Score math bit-identical to R7/R8 (same bf16rne, same ch=0..7 chain per
// code, same fadd(e2,-2*dot), same first-min {fkey|k} packing).
// latent [32,256,1024] fp32, codebook [1024,256] fp32.
// ws = [ Ebf bf16 chunk-planar [dq32][code1024][8] (512 KB) | e2 f32[1024] ].

#define D_   256
#define HW_  1024
#define N_   32768
#define K_   1024

typedef __attribute__((ext_vector_type(8))) short  s8v;   // 8 bf16 (4 VGPR)
typedef __attribute__((ext_vector_type(4))) float  f4v;   // MFMA acc

__device__ __forceinline__ ushort bf16rne(float x) {
  unsigned u = __float_as_uint(x);
  return (ushort)((u + 0x7FFFu + ((u >> 16) & 1u)) >> 16);
}

// monotone map: unsigned order of key == float order (handles negatives)
__device__ __forceinline__ unsigned fkey(float f) {
  unsigned u = __float_as_uint(f);
  return u ^ (unsigned)(((int)u >> 31) | 0x80000000);
}

// ---------- codebook -> bf16 chunk-planar Ebf + numpy-pairwise e2 + loss=0 ----------
// (unchanged — outputs must stay bit-identical)
__global__ __launch_bounds__(256) void k_eprep(const float* __restrict__ cb,
                                               ushort* __restrict__ Ebf,
                                               float* __restrict__ e2,
                                               float* __restrict__ loss) {
  const int t = threadIdx.x, blk = blockIdx.x;   // 64 blocks x 16 codes
  if (blk == 0 && t == 0) *loss = 0.f;
#pragma unroll
  for (int it = 0; it < 2; ++it) {
    int c = it * 256 + t;                        // 512 chunks/block
    int cl = c & 15, dq = c >> 4;                // code-local, d-chunk
    const float* src = cb + (size_t)(blk * 16 + cl) * 256 + dq * 8;
    float4 v0 = ((const float4*)src)[0], v1 = ((const float4*)src)[1];
    ushort tmp[8] __attribute__((aligned(16)));
    tmp[0] = bf16rne(v0.x); tmp[1] = bf16rne(v0.y);
    tmp[2] = bf16rne(v0.z); tmp[3] = bf16rne(v0.w);
    tmp[4] = bf16rne(v1.x); tmp[5] = bf16rne(v1.y);
    tmp[6] = bf16rne(v1.z); tmp[7] = bf16rne(v1.w);
    *(uint4*)(Ebf + ((size_t)dq * 1024 + blk * 16 + cl) * 8) = *(uint4*)tmp;
  }
  // e2 numpy-pairwise: 16 lanes/row, butterfly reproduces pairwise tree
  const int row = blk * 16 + (t >> 4);
  const int sub = t & 15, j = sub & 7, h = sub >> 3;
  const float* base = cb + row * 256 + h * 128 + j;
  float r = __fmul_rn(base[0], base[0]);
  for (int i = 1; i < 16; ++i) {
    float v = base[8 * i];
    r = __fadd_rn(r, __fmul_rn(v, v));
  }
#pragma unroll
  for (int m = 1; m < 16; m <<= 1) r = __fadd_rn(r, __shfl_xor(r, m, 64));
  if (sub == 0) e2[row] = r;
}

// ---------- fused: convert + MFMA-argmin over K=1024 + gather + out + loss ----------
// Grid 512 tiles (64 pos, hw-contiguous). Block 256 = 4 waves.
// LDS: Xbf 32 KB persistent A-operand [dq(32)][pos(64)][8] + e2s 4 KB +
// bests/red (~36.6 KB -> 3 blocks/CU at (256,3); 12 waves/CU).
// Wave tile 64 pos x 64 codes = acc[4][4]. B-fragments straight from global
// Ebf (L2-hit, 256 B per 16 lanes), 1-chunk-ahead prefetch, NO barriers in
// the K-loop.
__global__ __launch_bounds__(256, 3) void k_fused(
    const float* __restrict__ latent, const float* __restrict__ cb,
    const ushort* __restrict__ Ebf, const float* __restrict__ e2g,
    float* __restrict__ out, float* __restrict__ loss) {
  __shared__ alignas(16) ushort Xbf[32 * 64 * 8];   // 32 KB
  __shared__ alignas(16) float e2s[1024];           // 4 KB
  __shared__ unsigned long long bests[64];
  __shared__ float red[4];

  const int t = threadIdx.x, tile = blockIdx.x;     // 512 tiles x 64 pos
  const int b = tile >> 4, hw0 = (tile & 15) * 64;
  const int lane = t & 63, w = t >> 6;              // wave 0..3
  const int lrow = lane & 15, q = lane >> 4;

  ((float4*)e2s)[t] = ((const float4*)e2g)[t];      // 1024 floats, 256 thr
  if (t < 64) bests[t] = ~0ull;

  // ---- Phase A: latent tile -> Xbf (bf16, chunk-planar), register transpose ----
  const float* Lb = latent + (size_t)b * (D_ * HW_) + hw0;
#pragma unroll
  for (int itA = 0; itA < 2; ++itA) {
    const int id = itA * 256 + t;
    const int dq = id >> 4, pg = id & 15;           // d-chunk 0..31, pos-grp 0..15
    float4 v[8];
#pragma unroll
    for (int e = 0; e < 8; ++e)                     // coalesced: 16 lanes x 16 B
      v[e] = *(const float4*)(Lb + (size_t)(dq * 8 + e) * HW_ + pg * 4);
#pragma unroll
    for (int r = 0; r < 4; ++r) {
      ushort tmp[8] __attribute__((aligned(16)));
#pragma unroll
      for (int e = 0; e < 8; ++e) {
        float fv = (r == 0) ? v[e].x : (r == 1) ? v[e].y : (r == 2) ? v[e].z
                                                                    : v[e].w;
        tmp[e] = bf16rne(fv);
      }
      *(uint4*)&Xbf[((size_t)dq * 64 + pg * 4 + r) * 8] = *(uint4*)tmp;
    }
  }
  __syncthreads();                                   // Xbf + e2s + bests ready

  // ---- Phase B: K-loop over 1024 codes, argmin (NO barriers inside) ----
  // lane (q,lrow) of wave w: A row = pos mi*16+lrow, d-slice q of chunk ch;
  // B col = code kh + w*64 + kj*16 + lrow, same d-slice. B read from global.
  const ushort* Bb = Ebf + ((size_t)q * 1024 + w * 64 + lrow) * 8;

#pragma unroll 1
  for (int ms = 0; ms < 4; ++ms) {                   // 4 quarters of 256 codes
    const int kh = ms * 256;
    const ushort* Bh = Bb + (size_t)kh * 8;
    f4v acc[4][4];
#pragma unroll
    for (int mi = 0; mi < 4; ++mi)
#pragma unroll
      for (int kj = 0; kj < 4; ++kj) acc[mi][kj] = (f4v){0.f, 0.f, 0.f, 0.f};

    s8v b4[4];
#pragma unroll
    for (int kj = 0; kj < 4; ++kj)                   // prologue: chunk 0 B-frags
      b4[kj] = *(const s8v*)(Bh + kj * 128);

    for (int ch = 0; ch < 8; ++ch) {                 // chunks of 32 d
      s8v bn[4];
      if (ch < 7) {
#pragma unroll
        for (int kj = 0; kj < 4; ++kj)               // prefetch next chunk (L2)
          bn[kj] = *(const s8v*)(Bh + (size_t)(ch + 1) * 32768 + kj * 128);
      }
      s8v a_[4];
#pragma unroll
      for (int mi = 0; mi < 4; ++mi)
        a_[mi] = *(const s8v*)&Xbf[((size_t)(ch * 4 + q) * 64 + mi * 16 + lrow) * 8];
#pragma unroll
      for (int kj = 0; kj < 4; ++kj)
#pragma unroll
        for (int mi = 0; mi < 4; ++mi)
          acc[mi][kj] = __builtin_amdgcn_mfma_f32_16x16x32_bf16(
              a_[mi], b4[kj], acc[mi][kj], 0, 0, 0);
#pragma unroll
      for (int kj = 0; kj < 4; ++kj) b4[kj] = bn[kj];
    }

    // per-quarter epilogue: per-lane first-min over kj, 16-lane butterfly,
    // cross-wave/cross-quarter merge via atomicMin on {fkey|k}.
    float best[4][4];
    int bestk[4][4];
#pragma unroll
    for (int mi = 0; mi < 4; ++mi)
#pragma unroll
      for (int reg = 0; reg < 4; ++reg) { best[mi][reg] = 3.4e38f; bestk[mi][reg] = 0; }
#pragma unroll
    for (int kj = 0; kj < 4; ++kj) {                 // kj ascending: first-min
      int code = kh + w * 64 + kj * 16 + lrow;
      float e2v = e2s[code];
#pragma unroll
      for (int mi = 0; mi < 4; ++mi)
#pragma unroll
        for (int reg = 0; reg < 4; ++reg) {
          float s = __fadd_rn(e2v, -2.f * acc[mi][kj][reg]);
          if (s < best[mi][reg]) { best[mi][reg] = s; bestk[mi][reg] = code; }
        }
    }
#pragma unroll
    for (int mi = 0; mi < 4; ++mi)
#pragma unroll
      for (int reg = 0; reg < 4; ++reg) {
        float bv = best[mi][reg];
        int bk = bestk[mi][reg];
#pragma unroll
        for (int m = 1; m < 16; m <<= 1) {
          float ob = __shfl_xor(bv, m, 64);
          int ok = __shfl_xor(bk, m, 64);
          if (ob < bv || (ob == bv && ok < bk)) { bv = ob; bk = ok; }
        }
        if (lrow == 0) {
          int pos = mi * 16 + q * 4 + reg;
          atomicMin(&bests[pos],
                    ((unsigned long long)fkey(bv) << 32) | (unsigned)bk);
        }
      }
  }
  __syncthreads();                                   // bests final

  // ---- Phase C: gather + straight-through output + loss (R7 verbatim) ----
  const int posq = t & 15;                           // constant per thread
  int kk[4];
#pragma unroll
  for (int e = 0; e < 4; ++e)
    kk[e] = (int)(unsigned)(bests[posq * 4 + e] & 0xFFFFFFFFull);
  float* Ob = out + (size_t)b * (D_ * HW_) + hw0 + posq * 4;
  const float* Lb2 = Lb + posq * 4;
  float part = 0.f;
#pragma unroll 4
  for (int it = 0; it < 16; ++it) {
    int d = it * 16 + (t >> 4);
    float4 x = *(const float4*)(Lb2 + (size_t)d * HW_);
    float4 o;
    float qv, df;
    qv = cb[(size_t)kk[0] * 256 + d]; df = __fsub_rn(qv, x.x); o.x = __fadd_rn(x.x, df); part = fmaf(df, df, part);
    qv = cb[(size_t)kk[1] * 256 + d]; df = __fsub_rn(qv, x.y); o.y = __fadd_rn(x.y, df); part = fmaf(df, df, part);
    qv = cb[(size_t)kk[2] * 256 + d]; df = __fsub_rn(qv, x.z); o.z = __fadd_rn(x.z, df); part = fmaf(df, df, part);
    qv = cb[(size_t)kk[3] * 256 + d]; df = __fsub_rn(qv, x.w); o.w = __fadd_rn(x.w, df); part = fmaf(df, df, part);
    *(float4*)(Ob + (size_t)d * HW_) = o;            // x + (q - x), NOT q
  }
#pragma unroll
  for (int off = 32; off > 0; off >>= 1) part += __shfl_down(part, off, 64);
  if (lane == 0) red[w] = part;
  __syncthreads();
  if (t == 0)
    atomicAdd(loss, (red[0] + red[1] + red[2] + red[3]) * (1.25f / 8388608.0f));
}

extern "C" void kernel_launch(void* const* d_in, const int* in_sizes, int n_in,
                              void* d_out, int out_size, void* d_ws, size_t ws_size,
                              hipStream_t stream) {
  const float* latent = (const float*)d_in[0];
  const float* cb     = (const float*)d_in[1];
  float* out  = (float*)d_out;
  float* loss = out + (size_t)N_ * D_;             // element 8,388,608
  ushort* Ebf = (ushort*)d_ws;                     // 512 KB chunk-planar bf16
  float*  e2  = (float*)((char*)d_ws + (size_t)K_ * D_ * sizeof(ushort));

  hipLaunchKernelGGL(k_eprep, dim3(64),  dim3(256), 0, stream, cb, Ebf, e2, loss);
  hipLaunchKernelGGL(k_fused, dim3(512), dim3(256), 0, stream,
                     latent, cb, Ebf, e2, out, loss);
}

// Round 3
// 137.604 us; speedup vs baseline: 1.2388x; 1.2388x over previous
//
#include <hip/hip_runtime.h>
#include <stdint.h>

// VectorQuantizer on MI355X — round 10: R7 structure + 8-wave blocks (2x TLP).
// R8/R9 post-mortem: direct-global-B K-loop is register-starved (b4+bn+acc+
// best ~160 live) -> spills at every launch-bounds point with >=3 waves/SIMD
// (R8: +111 MB spill traffic; R9: +39 MB spill + L2 thrash, both ~100 us vs
// R7's 56). REVERT to R7's LDS-staged K-loop (FETCH 42 MB = ideal).
// R7's real limiter: grid 512 blocks = 2 blocks/CU resident -> 8 waves/CU =
// 2 waves/SIMD; the 16 stage->vmcnt(0)->barrier drains idle the SIMD (MfmaUtil
// 10.5%). Fix: 512-thread/8-wave blocks, wave tile 64 pos x 64 codes
// (acc[4][4]=64 regs, half of R7) -> 16 waves/CU = 4 waves/SIMD, same minimal
// Es traffic (each block reads Ebf once). Peak live ~105 <= 128-reg cap at
// (512,4); no global-B prefetch regs. unroll 1 on ms so halves' acc don't
// co-live. Score math bit-identical (same bf16rne, ch=0..7 MFMA chain,
// fadd(e2,-2*dot), first-min {fkey|k} packing — absmax invariant 0.001930237
// across R7/R8/R9 confirms mapping-independence).
// latent [32,256,1024] fp32, codebook [1024,256] fp32.
// ws = [ Ebf bf16 chunk-planar [dq32][code1024][8] (512 KB) | e2 f32[1024] ].

#define D_   256
#define HW_  1024
#define N_   32768
#define K_   1024

typedef __attribute__((ext_vector_type(8))) short  s8v;   // 8 bf16 (4 VGPR)
typedef __attribute__((ext_vector_type(4))) float  f4v;   // MFMA acc

__device__ __forceinline__ ushort bf16rne(float x) {
  unsigned u = __float_as_uint(x);
  return (ushort)((u + 0x7FFFu + ((u >> 16) & 1u)) >> 16);
}

// monotone map: unsigned order of key == float order (handles negatives)
__device__ __forceinline__ unsigned fkey(float f) {
  unsigned u = __float_as_uint(f);
  return u ^ (unsigned)(((int)u >> 31) | 0x80000000);
}

// async global->LDS DMA, 16 B/lane; LDS dest = wave-uniform base + lane*16
__device__ __forceinline__ void gld_lds16(const void* g, void* l) {
  __builtin_amdgcn_global_load_lds(
      (const __attribute__((address_space(1))) unsigned int*)g,
      (__attribute__((address_space(3))) unsigned int*)l, 16, 0, 0);
}

// ---------- codebook -> bf16 chunk-planar Ebf + numpy-pairwise e2 + loss=0 ----------
// (unchanged — outputs must stay bit-identical)
__global__ __launch_bounds__(256) void k_eprep(const float* __restrict__ cb,
                                               ushort* __restrict__ Ebf,
                                               float* __restrict__ e2,
                                               float* __restrict__ loss) {
  const int t = threadIdx.x, blk = blockIdx.x;   // 64 blocks x 16 codes
  if (blk == 0 && t == 0) *loss = 0.f;
#pragma unroll
  for (int it = 0; it < 2; ++it) {
    int c = it * 256 + t;                        // 512 chunks/block
    int cl = c & 15, dq = c >> 4;                // code-local, d-chunk
    const float* src = cb + (size_t)(blk * 16 + cl) * 256 + dq * 8;
    float4 v0 = ((const float4*)src)[0], v1 = ((const float4*)src)[1];
    ushort tmp[8] __attribute__((aligned(16)));
    tmp[0] = bf16rne(v0.x); tmp[1] = bf16rne(v0.y);
    tmp[2] = bf16rne(v0.z); tmp[3] = bf16rne(v0.w);
    tmp[4] = bf16rne(v1.x); tmp[5] = bf16rne(v1.y);
    tmp[6] = bf16rne(v1.z); tmp[7] = bf16rne(v1.w);
    *(uint4*)(Ebf + ((size_t)dq * 1024 + blk * 16 + cl) * 8) = *(uint4*)tmp;
  }
  // e2 numpy-pairwise: 16 lanes/row, butterfly reproduces pairwise tree
  const int row = blk * 16 + (t >> 4);
  const int sub = t & 15, j = sub & 7, h = sub >> 3;
  const float* base = cb + row * 256 + h * 128 + j;
  float r = __fmul_rn(base[0], base[0]);
  for (int i = 1; i < 16; ++i) {
    float v = base[8 * i];
    r = __fadd_rn(r, __fmul_rn(v, v));
  }
#pragma unroll
  for (int m = 1; m < 16; m <<= 1) r = __fadd_rn(r, __shfl_xor(r, m, 64));
  if (sub == 0) e2[row] = r;
}

// ---------- fused: convert + MFMA-argmin over K=1024 + gather + out + loss ----------
// Grid 512 tiles (64 pos, hw-contiguous). Block 512 = 8 waves.
// LDS: Xbf 32 KB persistent A-operand [dq(32)][pos(64)][8]; Es 32 KB
// [dqL(4)][code(512)][8] (phase-A Xf [64][68] f32 = 17.4 KB overlays it);
// bests 512 B; red 32 B -> ~66 KB -> 2 blocks/CU -> 16 waves/CU.
// Wave tile 64 pos x 64 codes = acc[4][4] (64 regs). Frag-read patterns
// identical bank-layout to R7's measured-low-conflict K-loop.
__global__ __launch_bounds__(512, 4) void k_fused(
    const float* __restrict__ latent, const float* __restrict__ cb,
    const ushort* __restrict__ Ebf, const float* __restrict__ e2g,
    float* __restrict__ out, float* __restrict__ loss) {
  __shared__ alignas(16) ushort Xbf[32 * 64 * 8];   // 32 KB
  __shared__ alignas(16) ushort Es[4 * 512 * 8];    // 32 KB (+phase-A Xf overlay)
  __shared__ unsigned long long bests[64];
  __shared__ float red[8];

  const int t = threadIdx.x, tile = blockIdx.x;     // 512 tiles x 64 pos
  const int b = tile >> 4, hw0 = (tile & 15) * 64;
  const int lane = t & 63, w = t >> 6;              // wave 0..7
  const int lrow = lane & 15, q = lane >> 4;

  if (t < 64) bests[t] = ~0ull;

  // ---- Phase A: latent tile -> Xbf (bf16, chunk-planar), via Xf overlay ----
  float* Xf = (float*)Es;                           // 64 x 68 fp32 = 17.4 KB
  const float* Lb = latent + (size_t)b * (D_ * HW_) + hw0;
  for (int s = 0; s < 4; ++s) {                     // slabs of 64 d
    __syncthreads();
#pragma unroll
    for (int it = 0; it < 2; ++it) {                // [64 d][64 hw] float4
      int id = it * 512 + t;
      int d = id >> 4, hq = id & 15;
      *(float4*)&Xf[d * 68 + hq * 4] =
          *(const float4*)(Lb + (size_t)(s * 64 + d) * HW_ + hq * 4);
    }
    __syncthreads();
    {                                               // transpose-convert, 512 units
      int pos = t & 63, dqs = t >> 6;               // dqs 0..7 in slab
      ushort tmp[8] __attribute__((aligned(16)));
#pragma unroll
      for (int e = 0; e < 8; ++e) tmp[e] = bf16rne(Xf[(dqs * 8 + e) * 68 + pos]);
      *(uint4*)&Xbf[((size_t)(s * 8 + dqs) * 64 + pos) * 8] = *(uint4*)tmp;
    }
  }

  // ---- Phase B: K-loop over 1024 codes in 2 halves, argmin ----
#pragma unroll 1
  for (int ms = 0; ms < 2; ++ms) {                  // halves of 512 codes
    const int kh = ms * 512;
    float e2q[4];
#pragma unroll
    for (int kj = 0; kj < 4; ++kj)                  // prefetch e2 (L2), hides latency
      e2q[kj] = e2g[kh + w * 64 + kj * 16 + lrow];

    f4v acc[4][4];
#pragma unroll
    for (int mi = 0; mi < 4; ++mi)
#pragma unroll
      for (int kj = 0; kj < 4; ++kj) acc[mi][kj] = (f4v){0.f, 0.f, 0.f, 0.f};

    for (int ch = 0; ch < 8; ++ch) {                // chunks of 32 d
      __syncthreads();                              // Es consumable (or overlay done)
#pragma unroll
      for (int ii = 0; ii < 4; ++ii) {              // stage Es: 32 KB, 4 insts/thread
        int jj = w * 4 + ii;                        // 0..31
        int dqL = jj >> 3, grp = jj & 7;
        gld_lds16(Ebf + ((size_t)(ch * 4 + dqL) * 1024 + kh + grp * 64 + lane) * 8,
                  &Es[((size_t)dqL * 512 + grp * 64 + lane) * 8]);
      }
      __syncthreads();                              // drain DMA
      s8v a_[4];                                    // q picks dq within chunk
#pragma unroll
      for (int mi = 0; mi < 4; ++mi)
        a_[mi] = *(const s8v*)&Xbf[((size_t)(ch * 4 + q) * 64 + mi * 16 + lrow) * 8];
#pragma unroll
      for (int kj = 0; kj < 4; ++kj) {
        s8v b_ = *(const s8v*)&Es[((size_t)q * 512 + w * 64 + kj * 16 + lrow) * 8];
#pragma unroll
        for (int mi = 0; mi < 4; ++mi)
          acc[mi][kj] = __builtin_amdgcn_mfma_f32_16x16x32_bf16(
              a_[mi], b_, acc[mi][kj], 0, 0, 0);
      }
    }

    // per-half epilogue: per-lane first-min over kj, 16-lane butterfly,
    // cross-wave/cross-half merge via atomicMin on {fkey|k}.
    float best[4][4];
    int bestk[4][4];
#pragma unroll
    for (int mi = 0; mi < 4; ++mi)
#pragma unroll
      for (int reg = 0; reg < 4; ++reg) { best[mi][reg] = 3.4e38f; bestk[mi][reg] = 0; }
#pragma unroll
    for (int kj = 0; kj < 4; ++kj) {                // kj ascending: first-min
      int code = kh + w * 64 + kj * 16 + lrow;
      float e2v = e2q[kj];
#pragma unroll
      for (int mi = 0; mi < 4; ++mi)
#pragma unroll
        for (int reg = 0; reg < 4; ++reg) {
          float s = __fadd_rn(e2v, -2.f * acc[mi][kj][reg]);
          if (s < best[mi][reg]) { best[mi][reg] = s; bestk[mi][reg] = code; }
        }
    }
#pragma unroll
    for (int mi = 0; mi < 4; ++mi)
#pragma unroll
      for (int reg = 0; reg < 4; ++reg) {
        float bv = best[mi][reg];
        int bk = bestk[mi][reg];
#pragma unroll
        for (int m = 1; m < 16; m <<= 1) {
          float ob = __shfl_xor(bv, m, 64);
          int ok = __shfl_xor(bk, m, 64);
          if (ob < bv || (ob == bv && ok < bk)) { bv = ob; bk = ok; }
        }
        if (lrow == 0) {
          int pos = mi * 16 + q * 4 + reg;
          atomicMin(&bests[pos],
                    ((unsigned long long)fkey(bv) << 32) | (unsigned)bk);
        }
      }
  }
  __syncthreads();                                  // bests final

  // ---- Phase C: gather + straight-through output + loss (512-thread, R9-proven) ----
  const int posq = t & 15;                          // pos-group of 4
  const int drow = t >> 4;                          // 0..31 d-slice
  int kk[4];
#pragma unroll
  for (int e = 0; e < 4; ++e)
    kk[e] = (int)(unsigned)(bests[posq * 4 + e] & 0xFFFFFFFFull);
  float* Ob = out + (size_t)b * (D_ * HW_) + hw0 + posq * 4;
  const float* Lb2 = Lb + posq * 4;
  float part = 0.f;
#pragma unroll 2
  for (int it = 0; it < 8; ++it) {
    int d = it * 32 + drow;
    float4 x = *(const float4*)(Lb2 + (size_t)d * HW_);
    float4 o;
    float qv, df;
    qv = cb[(size_t)kk[0] * 256 + d]; df = __fsub_rn(qv, x.x); o.x = __fadd_rn(x.x, df); part = fmaf(df, df, part);
    qv = cb[(size_t)kk[1] * 256 + d]; df = __fsub_rn(qv, x.y); o.y = __fadd_rn(x.y, df); part = fmaf(df, df, part);
    qv = cb[(size_t)kk[2] * 256 + d]; df = __fsub_rn(qv, x.z); o.z = __fadd_rn(x.z, df); part = fmaf(df, df, part);
    qv = cb[(size_t)kk[3] * 256 + d]; df = __fsub_rn(qv, x.w); o.w = __fadd_rn(x.w, df); part = fmaf(df, df, part);
    *(float4*)(Ob + (size_t)d * HW_) = o;           // x + (q - x), NOT q
  }
#pragma unroll
  for (int off = 32; off > 0; off >>= 1) part += __shfl_down(part, off, 64);
  if (lane == 0) red[w] = part;
  __syncthreads();
  if (t == 0) {
    float tot = 0.f;
#pragma unroll
    for (int i = 0; i < 8; ++i) tot += red[i];
    atomicAdd(loss, tot * (1.25f / 8388608.0f));
  }
}

extern "C" void kernel_launch(void* const* d_in, const int* in_sizes, int n_in,
                              void* d_out, int out_size, void* d_ws, size_t ws_size,
                              hipStream_t stream) {
  const float* latent = (const float*)d_in[0];
  const float* cb     = (const float*)d_in[1];
  float* out  = (float*)d_out;
  float* loss = out + (size_t)N_ * D_;             // element 8,388,608
  ushort* Ebf = (ushort*)d_ws;                     // 512 KB chunk-planar bf16
  float*  e2  = (float*)((char*)d_ws + (size_t)K_ * D_ * sizeof(ushort));

  hipLaunchKernelGGL(k_eprep, dim3(64),  dim3(256), 0, stream, cb, Ebf, e2, loss);
  hipLaunchKernelGGL(k_fused, dim3(512), dim3(512), 0, stream,
                     latent, cb, Ebf, e2, out, loss);
}

// Round 4
// 129.099 us; speedup vs baseline: 1.3204x; 1.0659x over previous
//
#include <hip/hip_runtime.h>
#include <stdint.h>

// VectorQuantizer on MI355X — round 11: dbuf pipeline + swapped-operand argmin.
// R10 post-mortem: 2x occupancy made it WORSE (67 vs 56 us): the serial
// stage->vmcnt(0)drain->compute structure doesn't overlap across lockstep
// blocks, and the 16-slot x 4-step butterfly epilogue (128 shuffles/thread/
// half) doubled with wave count (VALUBusy 14->21%).
// R11 fixes:
//  (1) T3 minimum-pipeline: Es double-buffered; STAGE(g+1) issued BEFORE
//      compute(g); single __syncthreads per chunk (its built-in vmcnt(0)
//      drain lands AFTER compute -> DMA overlapped). 1 barrier/chunk vs 2.
//  (2) T12 swap: mfma(b_, a_, acc) -> acc rows=codes, cols=pos. Per-lane
//      in-register first-min over 32 codes, then only 2 butterfly steps
//      (xor 16,32). Shuffles 128 -> 8 per thread-half. Scores bit-identical
//      (commutative elementwise mul, same k-order adder tree, same ch-chain),
//      same (score,code) first-min tie-break.
//  (3) 128-pos tiles: 256 blocks x 512 thr, 1 block/CU, 1 round. Halves
//      per-CU barrier phases and Es L2 traffic. LDS 129 KB; (512,2) ->
//      256-reg cap, live ~185, no spill expected (watch FETCH/WRITE symmetry).
// latent [32,256,1024] fp32, codebook [1024,256] fp32.
// ws = [ Ebf bf16 chunk-planar [dq32][code1024][8] (512 KB) | e2 f32[1024] ].

#define D_   256
#define HW_  1024
#define N_   32768
#define K_   1024

typedef __attribute__((ext_vector_type(8))) short  s8v;   // 8 bf16 (4 VGPR)
typedef __attribute__((ext_vector_type(4))) float  f4v;   // MFMA acc

__device__ __forceinline__ ushort bf16rne(float x) {
  unsigned u = __float_as_uint(x);
  return (ushort)((u + 0x7FFFu + ((u >> 16) & 1u)) >> 16);
}

// monotone map: unsigned order of key == float order (handles negatives)
__device__ __forceinline__ unsigned fkey(float f) {
  unsigned u = __float_as_uint(f);
  return u ^ (unsigned)(((int)u >> 31) | 0x80000000);
}

// async global->LDS DMA, 16 B/lane; LDS dest = wave-uniform base + lane*16
__device__ __forceinline__ void gld_lds16(const void* g, void* l) {
  __builtin_amdgcn_global_load_lds(
      (const __attribute__((address_space(1))) unsigned int*)g,
      (__attribute__((address_space(3))) unsigned int*)l, 16, 0, 0);
}

// ---------- codebook -> bf16 chunk-planar Ebf + numpy-pairwise e2 + loss=0 ----------
// widened to 128 blocks (8 codes each) for latency hiding; per-row math and
// output layout bit-identical to prior rounds.
__global__ __launch_bounds__(256) void k_eprep(const float* __restrict__ cb,
                                               ushort* __restrict__ Ebf,
                                               float* __restrict__ e2,
                                               float* __restrict__ loss) {
  const int t = threadIdx.x, blk = blockIdx.x;   // 128 blocks x 8 codes
  if (blk == 0 && t == 0) *loss = 0.f;
  {
    int cl = t & 7, dq = t >> 3;                 // code-local 0..7, d-chunk 0..31
    const float* src = cb + (size_t)(blk * 8 + cl) * 256 + dq * 8;
    float4 v0 = ((const float4*)src)[0], v1 = ((const float4*)src)[1];
    ushort tmp[8] __attribute__((aligned(16)));
    tmp[0] = bf16rne(v0.x); tmp[1] = bf16rne(v0.y);
    tmp[2] = bf16rne(v0.z); tmp[3] = bf16rne(v0.w);
    tmp[4] = bf16rne(v1.x); tmp[5] = bf16rne(v1.y);
    tmp[6] = bf16rne(v1.z); tmp[7] = bf16rne(v1.w);
    *(uint4*)(Ebf + ((size_t)dq * 1024 + blk * 8 + cl) * 8) = *(uint4*)tmp;
  }
  // e2 numpy-pairwise: 16 lanes/row, butterfly reproduces pairwise tree
  if (t < 128) {
    const int row = blk * 8 + (t >> 4);
    const int sub = t & 15, j = sub & 7, h = sub >> 3;
    const float* base = cb + row * 256 + h * 128 + j;
    float r = __fmul_rn(base[0], base[0]);
    for (int i = 1; i < 16; ++i) {
      float v = base[8 * i];
      r = __fadd_rn(r, __fmul_rn(v, v));
    }
#pragma unroll
    for (int m = 1; m < 16; m <<= 1) r = __fadd_rn(r, __shfl_xor(r, m, 64));
    if (sub == 0) e2[row] = r;
  }
}

// ---------- fused: convert + MFMA-argmin over K=1024 + gather + out + loss ----------
// Grid 256 tiles (128 pos, hw-contiguous). Block 512 = 8 waves (2M x 4K).
// LDS: Xbf 64 KB [dq32][pos128][8]; Es dbuf 2x32 KB (phase-A Xf [64][132]
// overlay); e2s 4 KB; bests 1 KB -> ~129 KB -> 1 block/CU.
// Wave (wr=w>>2, wc=w&3): 64 pos x 128 codes per 512-half; acc[8][4] with
// SWAPPED operands: rows=codes (q*4+reg), cols=pos (lrow).
__global__ __launch_bounds__(512, 2) void k_fused(
    const float* __restrict__ latent, const float* __restrict__ cb,
    const ushort* __restrict__ Ebf, const float* __restrict__ e2g,
    float* __restrict__ out, float* __restrict__ loss) {
  __shared__ alignas(16) ushort Xbf[32 * 128 * 8];   // 64 KB
  __shared__ alignas(16) ushort Es[2][4 * 512 * 8];  // 64 KB (+phase-A Xf overlay)
  __shared__ alignas(16) float e2s[1024];            // 4 KB
  __shared__ unsigned long long bests[128];          // 1 KB
  __shared__ float red[8];

  const int t = threadIdx.x, tile = blockIdx.x;      // 256 tiles x 128 pos
  const int b = tile >> 3, hw0 = (tile & 7) * 128;
  const int lane = t & 63, w = t >> 6;               // wave 0..7
  const int lrow = lane & 15, q = lane >> 4;
  const int wr = w >> 2, wc = w & 3;                 // pos-half, code-sub

  ((float2*)e2s)[t] = ((const float2*)e2g)[t];       // 1024 floats, 512 thr
  if (t < 128) bests[t] = ~0ull;

  // ---- Phase A: latent tile -> Xbf (bf16, chunk-planar), via Xf overlay ----
  float* Xf = (float*)Es;                            // [64][132] f32 = 33.8 KB
  const float* Lb = latent + (size_t)b * (D_ * HW_) + hw0;
  for (int s = 0; s < 4; ++s) {                      // slabs of 64 d
    __syncthreads();
#pragma unroll
    for (int it = 0; it < 4; ++it) {                 // [64 d][128 hw] float4
      int id = it * 512 + t;
      int d = id >> 5, hq = id & 31;
      *(float4*)&Xf[d * 132 + hq * 4] =
          *(const float4*)(Lb + (size_t)(s * 64 + d) * HW_ + hq * 4);
    }
    __syncthreads();
#pragma unroll
    for (int it = 0; it < 2; ++it) {                 // transpose-convert
      int id = it * 512 + t;
      int pos = id & 127, dqs = id >> 7;             // dqs 0..7 in slab
      ushort tmp[8] __attribute__((aligned(16)));
#pragma unroll
      for (int e = 0; e < 8; ++e) tmp[e] = bf16rne(Xf[(dqs * 8 + e) * 132 + pos]);
      *(uint4*)&Xbf[((size_t)(s * 8 + dqs) * 128 + pos) * 8] = *(uint4*)tmp;
    }
  }
  __syncthreads();                                   // Xf dead -> Es stageable

  // ---- Phase B: pipelined K-loop, 16 chunk-phases (2 halves x 8 chunks) ----
#define STAGE_ES(J)                                                           \
  {                                                                           \
    const int chS = (J) & 7, khS = ((J) >> 3) << 9, bufS = (J) & 1;           \
    _Pragma("unroll")                                                         \
    for (int ii = 0; ii < 4; ++ii) {                                          \
      int jj = w * 4 + ii;                                                    \
      int dqL = jj >> 3, grp = jj & 7;                                        \
      gld_lds16(                                                              \
          Ebf + ((size_t)(chS * 4 + dqL) * 1024 + khS + grp * 64 + lane) * 8, \
          &Es[bufS][((size_t)dqL * 512 + grp * 64 + lane) * 8]);              \
    }                                                                         \
  }

  f4v acc[8][4];                                     // [code-sub kj][pos-sub mi]
  STAGE_ES(0);
  __syncthreads();                                   // drain: buf0 ready

#pragma unroll 1
  for (int g = 0; g < 16; ++g) {                     // g = half*8 + chunk
    if (g < 15) STAGE_ES(g + 1);                     // issue next; overlaps below
    const int ch = g & 7, buf = g & 1;
    if (ch == 0) {
#pragma unroll
      for (int kj = 0; kj < 8; ++kj)
#pragma unroll
        for (int mi = 0; mi < 4; ++mi) acc[kj][mi] = (f4v){0.f, 0.f, 0.f, 0.f};
    }
    s8v a_[4];
#pragma unroll
    for (int mi = 0; mi < 4; ++mi)
      a_[mi] = *(const s8v*)
          &Xbf[((size_t)(ch * 4 + q) * 128 + wr * 64 + mi * 16 + lrow) * 8];
#pragma unroll
    for (int kj = 0; kj < 8; ++kj) {
      s8v b_ = *(const s8v*)
          &Es[buf][((size_t)q * 512 + wc * 128 + kj * 16 + lrow) * 8];
#pragma unroll
      for (int mi = 0; mi < 4; ++mi)                 // SWAPPED: rows=codes
        acc[kj][mi] = __builtin_amdgcn_mfma_f32_16x16x32_bf16(
            b_, a_[mi], acc[kj][mi], 0, 0, 0);
    }
    if (ch == 7) {                                   // per-half epilogue
      const int kh = (g >> 3) << 9;
#pragma unroll
      for (int mi = 0; mi < 4; ++mi) {               // pos = wr*64+mi*16+lrow
        float bv = 3.4e38f;
        int bk = 0;
#pragma unroll
        for (int kj = 0; kj < 8; ++kj)               // ascending code order:
#pragma unroll
          for (int reg = 0; reg < 4; ++reg) {        // first-min on ties
            int code = kh + wc * 128 + kj * 16 + q * 4 + reg;
            float s = __fadd_rn(e2s[code], -2.f * acc[kj][mi][reg]);
            if (s < bv) { bv = s; bk = code; }
          }
#pragma unroll
        for (int m = 16; m < 64; m <<= 1) {          // reduce over q: 2 steps
          float ob = __shfl_xor(bv, m, 64);
          int ok = __shfl_xor(bk, m, 64);
          if (ob < bv || (ob == bv && ok < bk)) { bv = ob; bk = ok; }
        }
        if (q == 0)
          atomicMin(&bests[wr * 64 + mi * 16 + lrow],
                    ((unsigned long long)fkey(bv) << 32) | (unsigned)bk);
      }
    }
    __syncthreads();                                 // drains my STAGE(g+1) too
  }
  // bests final (last loop barrier)

  // ---- Phase C: gather + straight-through output + loss ----
  const int posq = t & 31;                           // pos-group of 4 (0..31)
  const int drow = t >> 5;                           // 0..15 d-slice
  int kk[4];
#pragma unroll
  for (int e = 0; e < 4; ++e)
    kk[e] = (int)(unsigned)(bests[posq * 4 + e] & 0xFFFFFFFFull);
  float* Ob = out + (size_t)b * (D_ * HW_) + hw0 + posq * 4;
  const float* Lb2 = Lb + posq * 4;
  float part = 0.f;
#pragma unroll 2
  for (int it = 0; it < 16; ++it) {
    int d = it * 16 + drow;
    float4 x = *(const float4*)(Lb2 + (size_t)d * HW_);
    float4 o;
    float qv, df;
    qv = cb[(size_t)kk[0] * 256 + d]; df = __fsub_rn(qv, x.x); o.x = __fadd_rn(x.x, df); part = fmaf(df, df, part);
    qv = cb[(size_t)kk[1] * 256 + d]; df = __fsub_rn(qv, x.y); o.y = __fadd_rn(x.y, df); part = fmaf(df, df, part);
    qv = cb[(size_t)kk[2] * 256 + d]; df = __fsub_rn(qv, x.z); o.z = __fadd_rn(x.z, df); part = fmaf(df, df, part);
    qv = cb[(size_t)kk[3] * 256 + d]; df = __fsub_rn(qv, x.w); o.w = __fadd_rn(x.w, df); part = fmaf(df, df, part);
    *(float4*)(Ob + (size_t)d * HW_) = o;            // x + (q - x), NOT q
  }
#pragma unroll
  for (int off = 32; off > 0; off >>= 1) part += __shfl_down(part, off, 64);
  if (lane == 0) red[w] = part;
  __syncthreads();
  if (t == 0) {
    float tot = 0.f;
#pragma unroll
    for (int i = 0; i < 8; ++i) tot += red[i];
    atomicAdd(loss, tot * (1.25f / 8388608.0f));
  }
}

extern "C" void kernel_launch(void* const* d_in, const int* in_sizes, int n_in,
                              void* d_out, int out_size, void* d_ws, size_t ws_size,
                              hipStream_t stream) {
  const float* latent = (const float*)d_in[0];
  const float* cb     = (const float*)d_in[1];
  float* out  = (float*)d_out;
  float* loss = out + (size_t)N_ * D_;             // element 8,388,608
  ushort* Ebf = (ushort*)d_ws;                     // 512 KB chunk-planar bf16
  float*  e2  = (float*)((char*)d_ws + (size_t)K_ * D_ * sizeof(ushort));

  hipLaunchKernelGGL(k_eprep, dim3(128), dim3(256), 0, stream, cb, Ebf, e2, loss);
  hipLaunchKernelGGL(k_fused, dim3(256), dim3(512), 0, stream,
                     latent, cb, Ebf, e2, out, loss);
}

// Round 6
// 126.346 us; speedup vs baseline: 1.3492x; 1.0218x over previous
//
#include <hip/hip_runtime.h>
#include <stdint.h>

// VectorQuantizer on MI355X — round 12b: resubmit of R12 (container infra
// flake; kernel audited: no deadlock path — uniform barriers, own-wave vmcnt
// pre-rendezvous; no OOB — Xf/Xbf/Es/Ebf indices bounded, bests[] always
// written so phase-C gather index is in [0,1023]).
// R12 design: 2 blocks/CU + true depth-1 pipeline.
// R11 post-mortem: MfmaUtil is pinned at (6.7us MFMA-work / dur) — the CU
// waits ~50us. Cross-round: R7(2blk/CU, bad struct)=56, R11(1blk/CU, good
// struct)=57, R10(2blk/CU, heavy epilogue)=67 -> barrier-convoy/TLP regime:
// with 1 block/CU every full-block barrier idles the CU. Also R11's
// __syncthreads drained the SAME-iteration STAGE (half-depth pipeline).
// R12: (a) 64-pos tiles, 512 thr, LDS ~69 KB -> 2 blocks/CU = 16 waves/CU;
// (b) T3 pipeline with raw s_barrier + own-wave vmcnt(0) placed BEFORE the
// rendezvous: [vmcnt(0) -> sched_barrier -> s_barrier -> STAGE(g+1) ->
// compute(g)] — staged loads get a full phase to land, no compiler drain.
// (c) wave tile 64 pos x 32 codes, acc[2][4]=32 regs, live ~90 <= 128 cap
// at (512,4) (spill tripwire: FETCH/WRITE symmetry).
// Score math bit-identical to R7..R11 (absmax invariant 0.001930237).
// latent [32,256,1024] fp32, codebook [1024,256] fp32.
// ws = [ Ebf bf16 chunk-planar [dq32][code1024][8] (512 KB) | e2 f32[1024] ].

#define D_   256
#define HW_  1024
#define N_   32768
#define K_   1024

typedef __attribute__((ext_vector_type(8))) short  s8v;   // 8 bf16 (4 VGPR)
typedef __attribute__((ext_vector_type(4))) float  f4v;   // MFMA acc

__device__ __forceinline__ ushort bf16rne(float x) {
  unsigned u = __float_as_uint(x);
  return (ushort)((u + 0x7FFFu + ((u >> 16) & 1u)) >> 16);
}

// monotone map: unsigned order of key == float order (handles negatives)
__device__ __forceinline__ unsigned fkey(float f) {
  unsigned u = __float_as_uint(f);
  return u ^ (unsigned)(((int)u >> 31) | 0x80000000);
}

// async global->LDS DMA, 16 B/lane; LDS dest = wave-uniform base + lane*16
__device__ __forceinline__ void gld_lds16(const void* g, void* l) {
  __builtin_amdgcn_global_load_lds(
      (const __attribute__((address_space(1))) unsigned int*)g,
      (__attribute__((address_space(3))) unsigned int*)l, 16, 0, 0);
}

// ---------- codebook -> bf16 chunk-planar Ebf + numpy-pairwise e2 + loss=0 ----------
// (unchanged from R11 — outputs bit-identical)
__global__ __launch_bounds__(256) void k_eprep(const float* __restrict__ cb,
                                               ushort* __restrict__ Ebf,
                                               float* __restrict__ e2,
                                               float* __restrict__ loss) {
  const int t = threadIdx.x, blk = blockIdx.x;   // 128 blocks x 8 codes
  if (blk == 0 && t == 0) *loss = 0.f;
  {
    int cl = t & 7, dq = t >> 3;                 // code-local 0..7, d-chunk 0..31
    const float* src = cb + (size_t)(blk * 8 + cl) * 256 + dq * 8;
    float4 v0 = ((const float4*)src)[0], v1 = ((const float4*)src)[1];
    ushort tmp[8] __attribute__((aligned(16)));
    tmp[0] = bf16rne(v0.x); tmp[1] = bf16rne(v0.y);
    tmp[2] = bf16rne(v0.z); tmp[3] = bf16rne(v0.w);
    tmp[4] = bf16rne(v1.x); tmp[5] = bf16rne(v1.y);
    tmp[6] = bf16rne(v1.z); tmp[7] = bf16rne(v1.w);
    *(uint4*)(Ebf + ((size_t)dq * 1024 + blk * 8 + cl) * 8) = *(uint4*)tmp;
  }
  // e2 numpy-pairwise: 16 lanes/row, butterfly reproduces pairwise tree
  if (t < 128) {
    const int row = blk * 8 + (t >> 4);
    const int sub = t & 15, j = sub & 7, h = sub >> 3;
    const float* base = cb + row * 256 + h * 128 + j;
    float r = __fmul_rn(base[0], base[0]);
    for (int i = 1; i < 16; ++i) {
      float v = base[8 * i];
      r = __fadd_rn(r, __fmul_rn(v, v));
    }
#pragma unroll
    for (int m = 1; m < 16; m <<= 1) r = __fadd_rn(r, __shfl_xor(r, m, 64));
    if (sub == 0) e2[row] = r;
  }
}

// ---------- fused: convert + MFMA-argmin over K=1024 + gather + out + loss ----------
// Grid 512 tiles (64 pos, hw-contiguous). Block 512 = 8 waves.
// LDS: Xbf 32 KB [dq32][pos64][8]; Es dbuf 2x16 KB [dqL4][code256][8]
// (phase-A Xf [64][68] f32 = 17.4 KB overlays the Es pair); e2s 4 KB;
// bests 512 B -> ~69 KB -> 2 blocks/CU -> 16 waves/CU.
// 32 phases = 4 quarters (256 codes) x 8 chunks (32 d). Wave w: 64 pos x
// 32 codes (w*32 within quarter), acc[2][4] swapped (rows=codes, cols=pos).
__global__ __launch_bounds__(512, 4) void k_fused(
    const float* __restrict__ latent, const float* __restrict__ cb,
    const ushort* __restrict__ Ebf, const float* __restrict__ e2g,
    float* __restrict__ out, float* __restrict__ loss) {
  __shared__ alignas(16) ushort Xbf[32 * 64 * 8];    // 32 KB
  __shared__ alignas(16) ushort Es[2][4 * 256 * 8];  // 2x16 KB (+Xf overlay)
  __shared__ alignas(16) float e2s[1024];            // 4 KB
  __shared__ unsigned long long bests[64];           // 512 B
  __shared__ float red[8];

  const int t = threadIdx.x, tile = blockIdx.x;      // 512 tiles x 64 pos
  const int b = tile >> 4, hw0 = (tile & 15) * 64;
  const int lane = t & 63, w = t >> 6;               // wave 0..7
  const int lrow = lane & 15, q = lane >> 4;

  ((float2*)e2s)[t] = ((const float2*)e2g)[t];       // 1024 floats, 512 thr
  if (t < 64) bests[t] = ~0ull;

  // ---- Phase A: latent tile -> Xbf (bf16, chunk-planar), via Xf overlay ----
  float* Xf = (float*)Es;                            // [64][68] f32 = 17.4 KB
  const float* Lb = latent + (size_t)b * (D_ * HW_) + hw0;
  for (int s = 0; s < 4; ++s) {                      // slabs of 64 d
    __syncthreads();
#pragma unroll
    for (int it = 0; it < 2; ++it) {                 // [64 d][64 hw] float4
      int id = it * 512 + t;
      int d = id >> 4, hq = id & 15;
      *(float4*)&Xf[d * 68 + hq * 4] =
          *(const float4*)(Lb + (size_t)(s * 64 + d) * HW_ + hq * 4);
    }
    __syncthreads();
    {                                                // transpose-convert
      int pos = t & 63, dqs = t >> 6;                // dqs 0..7 in slab
      ushort tmp[8] __attribute__((aligned(16)));
#pragma unroll
      for (int e = 0; e < 8; ++e) tmp[e] = bf16rne(Xf[(dqs * 8 + e) * 68 + pos]);
      *(uint4*)&Xbf[((size_t)(s * 8 + dqs) * 64 + pos) * 8] = *(uint4*)tmp;
    }
  }
  __syncthreads();                                   // Xf dead; Xbf/e2s/bests ready

  // ---- Phase B: 32 pipelined phases (quarter qt = g>>3, chunk ch = g&7) ----
  // STAGE(J): DMA quarter/chunk of Ebf -> Es[J&1]; 2 insts/wave (16/block).
#define STAGE_ES(J)                                                           \
  {                                                                           \
    const int chS = (J) & 7, kqS = ((J) >> 3) << 8, bufS = (J) & 1;           \
    _Pragma("unroll")                                                         \
    for (int ii = 0; ii < 2; ++ii) {                                          \
      int jj = w * 2 + ii;                           /* 0..15 */              \
      int dqL = jj >> 2, grp = jj & 3;               /* 4 dq x 4 grp */       \
      gld_lds16(                                                              \
          Ebf + ((size_t)(chS * 4 + dqL) * 1024 + kqS + grp * 64 + lane) * 8, \
          &Es[bufS][((size_t)dqL * 256 + grp * 64 + lane) * 8]);              \
    }                                                                         \
  }

  f4v acc[2][4];                                     // [code-sub kj][pos-sub mi]
  STAGE_ES(0);                                       // after barrier: Xf dead

#pragma unroll 1
  for (int g = 0; g < 32; ++g) {
    // my STAGE(g) loads (issued last phase) are the only outstanding vmem
    asm volatile("s_waitcnt vmcnt(0)" ::: "memory");
    __builtin_amdgcn_sched_barrier(0);
    __builtin_amdgcn_s_barrier();                    // all waves: buf[g&1] full,
    __builtin_amdgcn_sched_barrier(0);               // prev reads of buf[g^1] done
    if (g < 31) STAGE_ES(g + 1);                     // overwrite-safe post-barrier

    const int ch = g & 7, buf = g & 1;
    if (ch == 0) {
#pragma unroll
      for (int kj = 0; kj < 2; ++kj)
#pragma unroll
        for (int mi = 0; mi < 4; ++mi) acc[kj][mi] = (f4v){0.f, 0.f, 0.f, 0.f};
    }
    s8v a_[4];
#pragma unroll
    for (int mi = 0; mi < 4; ++mi)
      a_[mi] = *(const s8v*)&Xbf[((size_t)(ch * 4 + q) * 64 + mi * 16 + lrow) * 8];
#pragma unroll
    for (int kj = 0; kj < 2; ++kj) {
      s8v b_ = *(const s8v*)&Es[buf][((size_t)q * 256 + w * 32 + kj * 16 + lrow) * 8];
#pragma unroll
      for (int mi = 0; mi < 4; ++mi)                 // SWAPPED: rows=codes
        acc[kj][mi] = __builtin_amdgcn_mfma_f32_16x16x32_bf16(
            b_, a_[mi], acc[kj][mi], 0, 0, 0);
    }
    if (ch == 7) {                                   // per-quarter epilogue
      const int kq = (g >> 3) << 8;
#pragma unroll
      for (int mi = 0; mi < 4; ++mi) {               // pos = mi*16+lrow
        float bv = 3.4e38f;
        int bk = 0;
#pragma unroll
        for (int kj = 0; kj < 2; ++kj)               // ascending code order:
#pragma unroll
          for (int reg = 0; reg < 4; ++reg) {        // first-min on ties
            int code = kq + w * 32 + kj * 16 + q * 4 + reg;
            float s = __fadd_rn(e2s[code], -2.f * acc[kj][mi][reg]);
            if (s < bv) { bv = s; bk = code; }
          }
#pragma unroll
        for (int m = 16; m < 64; m <<= 1) {          // reduce over q: 2 steps
          float ob = __shfl_xor(bv, m, 64);
          int ok = __shfl_xor(bk, m, 64);
          if (ob < bv || (ob == bv && ok < bk)) { bv = ob; bk = ok; }
        }
        if (q == 0)
          atomicMin(&bests[mi * 16 + lrow],
                    ((unsigned long long)fkey(bv) << 32) | (unsigned)bk);
      }
    }
  }
  __syncthreads();                                   // bests final (drains all)

  // ---- Phase C: gather + straight-through output + loss ----
  const int posq = t & 15;                           // pos-group of 4
  const int drow = t >> 4;                           // 0..31 d-slice
  int kk[4];
#pragma unroll
  for (int e = 0; e < 4; ++e)
    kk[e] = (int)(unsigned)(bests[posq * 4 + e] & 0xFFFFFFFFull);
  float* Ob = out + (size_t)b * (D_ * HW_) + hw0 + posq * 4;
  const float* Lb2 = Lb + posq * 4;
  float part = 0.f;
#pragma unroll 2
  for (int it = 0; it < 8; ++it) {
    int d = it * 32 + drow;
    float4 x = *(const float4*)(Lb2 + (size_t)d * HW_);
    float4 o;
    float qv, df;
    qv = cb[(size_t)kk[0] * 256 + d]; df = __fsub_rn(qv, x.x); o.x = __fadd_rn(x.x, df); part = fmaf(df, df, part);
    qv = cb[(size_t)kk[1] * 256 + d]; df = __fsub_rn(qv, x.y); o.y = __fadd_rn(x.y, df); part = fmaf(df, df, part);
    qv = cb[(size_t)kk[2] * 256 + d]; df = __fsub_rn(qv, x.z); o.z = __fadd_rn(x.z, df); part = fmaf(df, df, part);
    qv = cb[(size_t)kk[3] * 256 + d]; df = __fsub_rn(qv, x.w); o.w = __fadd_rn(x.w, df); part = fmaf(df, df, part);
    *(float4*)(Ob + (size_t)d * HW_) = o;            // x + (q - x), NOT q
  }
#pragma unroll
  for (int off = 32; off > 0; off >>= 1) part += __shfl_down(part, off, 64);
  if (lane == 0) red[w] = part;
  __syncthreads();
  if (t == 0) {
    float tot = 0.f;
#pragma unroll
    for (int i = 0; i < 8; ++i) tot += red[i];
    atomicAdd(loss, tot * (1.25f / 8388608.0f));
  }
}

extern "C" void kernel_launch(void* const* d_in, const int* in_sizes, int n_in,
                              void* d_out, int out_size, void* d_ws, size_t ws_size,
                              hipStream_t stream) {
  const float* latent = (const float*)d_in[0];
  const float* cb     = (const float*)d_in[1];
  float* out  = (float*)d_out;
  float* loss = out + (size_t)N_ * D_;             // element 8,388,608
  ushort* Ebf = (ushort*)d_ws;                     // 512 KB chunk-planar bf16
  float*  e2  = (float*)((char*)d_ws + (size_t)K_ * D_ * sizeof(ushort));

  hipLaunchKernelGGL(k_eprep, dim3(128), dim3(256), 0, stream, cb, Ebf, e2, loss);
  hipLaunchKernelGGL(k_fused, dim3(512), dim3(512), 0, stream,
                     latent, cb, Ebf, e2, out, loss);
}